// Round 1
// baseline (575.771 us; speedup 1.0000x reference)
//
#include <hip/hip_runtime.h>
#include <hip/hip_bf16.h>

#define IN_CH 512
#define OUT_CH 512
#define HW 64
#define BATCH 16
#define WEIGHT_GAIN 0.014731391274719739f    // 1/sqrt(512*9)
#define MOD_WEIGHT_GAIN 0.04419417382415922f // 1/sqrt(512)

// padded NHWC xs buffer: [B][66][66][512] bf16
#define PAD_W 66
#define XS_PIX_STRIDE 512

typedef __attribute__((ext_vector_type(8))) short frag8;
typedef __attribute__((ext_vector_type(4))) float f32x4;

// ---------------- style[b][i] = sum_j w[b][j]*mw[i][j]*g + mb[i] ----------------
__global__ void style_kernel(const float* __restrict__ w, const float* __restrict__ mw,
                             const float* __restrict__ mb, float* __restrict__ style) {
    __shared__ float wsh[512];
    const int b = blockIdx.x;
    const int i = threadIdx.x;
    wsh[i] = w[b * 512 + i];
    __syncthreads();
    const float4* row = (const float4*)(mw + i * 512);
    float s = 0.f;
#pragma unroll 4
    for (int j = 0; j < 128; ++j) {
        float4 v = row[j];
        const float* ws = &wsh[j * 4];
        s += v.x * ws[0] + v.y * ws[1] + v.z * ws[2] + v.w * ws[3];
    }
    style[b * 512 + i] = s * MOD_WEIGHT_GAIN + mb[i];
}

// ---------------- wsq[o][i] = G^2 * sum_kk weight^2 ; wbf[kk][o][i] = bf16(weight) ----
__global__ void wprep_kernel(const float* __restrict__ weight, float* __restrict__ wsq,
                             __hip_bfloat16* __restrict__ wbf) {
    const int idx = blockIdx.x * 256 + threadIdx.x;   // 0..262143 = o*512+i
    const float* wp = weight + idx * 9;
    float s = 0.f;
#pragma unroll
    for (int kk = 0; kk < 9; ++kk) {
        float v = wp[kk];
        s += v * v;
        wbf[kk * 262144 + idx] = __float2bfloat16(v);
    }
    wsq[idx] = s * (WEIGHT_GAIN * WEIGHT_GAIN);
}

// ---------------- sc[b][o] = G * rsqrt(sum_i style^2 * wsq + 1e-8) -------------------
__global__ void demod_kernel(const float* __restrict__ style, const float* __restrict__ wsq,
                             float* __restrict__ sc) {
    __shared__ float s2[512];
    const int b = blockIdx.x;
    const int o = threadIdx.x;
    float st = style[b * 512 + o];
    s2[o] = st * st;
    __syncthreads();
    const float4* row = (const float4*)(wsq + o * 512);
    float acc = 0.f;
#pragma unroll 4
    for (int j = 0; j < 128; ++j) {
        float4 v = row[j];
        const float* ss = &s2[j * 4];
        acc += v.x * ss[0] + v.y * ss[1] + v.z * ss[2] + v.w * ss[3];
    }
    sc[b * 512 + o] = rsqrtf(acc + 1e-8f) * WEIGHT_GAIN;
}

// ---------------- xs_pad[b][y+1][x+1][i] = bf16(style[b][i] * x[b][i][y][x]) ---------
// NCHW fp32 -> padded NHWC bf16 transpose via LDS tile
__global__ void xs_kernel(const float* __restrict__ x, const float* __restrict__ style,
                          __hip_bfloat16* __restrict__ xsp) {
    __shared__ float tile[64][65];
    const int y = blockIdx.x;     // image row
    const int i0 = blockIdx.y * 64;
    const int b = blockIdx.z;
    const int t = threadIdx.x;

    // load 64 channels x 64 cols, scaled by style
    {
        const int ii = t >> 2;
        const int x0 = (t & 3) * 16;
        const float st = style[b * 512 + i0 + ii];
        const float4* s4 = (const float4*)(x + (((size_t)b * 512 + i0 + ii) * 64 + y) * 64 + x0);
#pragma unroll
        for (int k4 = 0; k4 < 4; ++k4) {
            float4 v = s4[k4];
            float* d = &tile[ii][x0 + k4 * 4];
            d[0] = v.x * st; d[1] = v.y * st; d[2] = v.z * st; d[3] = v.w * st;
        }
    }
    __syncthreads();
    // write transposed: for pixel (y, xx), 16 consecutive channels per thread
    {
        const int xx = t >> 2;
        const int j0 = (t & 3) * 16;
        __hip_bfloat16* dst = xsp + (((size_t)b * PAD_W + (y + 1)) * PAD_W + (xx + 1)) * XS_PIX_STRIDE + i0 + j0;
        union { __hip_bfloat16 h[16]; uint4 u[2]; } pk;
#pragma unroll
        for (int k = 0; k < 16; ++k) pk.h[k] = __float2bfloat16(tile[j0 + k][xx]);
        ((uint4*)dst)[0] = pk.u[0];
        ((uint4*)dst)[1] = pk.u[1];
    }
}

// ---------------- conv: implicit GEMM, M=512(o) x N=4096(p) per batch, K=9*512 -------
// A = wbf[kk][o][i] (bf16, i contiguous), B = xs_pad pixels (bf16, i contiguous)
// 128x128 tile, BK=64, 4 waves each doing 4x4 16x16x32 MFMA tiles.
__global__ void conv_kernel(const __hip_bfloat16* __restrict__ wbf,
                            const __hip_bfloat16* __restrict__ xsp,
                            const float* __restrict__ sc,
                            float* __restrict__ out) {
    __shared__ __hip_bfloat16 ash[128 * 64];
    __shared__ __hip_bfloat16 bsh[128 * 64];

    const int t = threadIdx.x;
    const int p0 = blockIdx.x * 128;   // spatial tile (2 full rows)
    const int m0 = blockIdx.y * 128;   // output-channel tile
    const int b  = blockIdx.z;
    const int y0 = p0 >> 6;

    // --- staging thread mapping: inst q covers tile rows [q*32, q*32+32) ---
    const int r_base = t >> 3;               // 0..31
    const int s_slot = (t & 7) ^ (r_base & 7); // XOR-swizzled source k-group
    const int aoff = (m0 + r_base) * 512 + s_slot * 8;
    int pixoff[4];
#pragma unroll
    for (int q = 0; q < 4; ++q) {
        const int rB = q * 32 + r_base;
        const int yy = y0 + (rB >> 6);       // un-shifted padded row - 0 (tap adds ky)
        const int xx = rB & 63;
        pixoff[q] = (((b * PAD_W) + yy) * PAD_W + xx) * XS_PIX_STRIDE + s_slot * 8;
    }

    // --- compute thread mapping ---
    const int wv = t >> 6;
    const int wm = (wv >> 1) * 64;
    const int wn = (wv & 1) * 64;
    const int lane = t & 63;
    const int ln15 = lane & 15;
    const int quad = lane >> 4;

    f32x4 acc[4][4] = {};

    const short* ashp = (const short*)ash;
    const short* bshp = (const short*)bsh;

    for (int kk = 0; kk < 9; ++kk) {
        const __hip_bfloat16* wsrc = wbf + kk * 262144 + aoff;
        const int shift = ((kk / 3) * PAD_W + (kk % 3)) * XS_PIX_STRIDE;
        const __hip_bfloat16* xbase = xsp + shift;

        for (int c0 = 0; c0 < 512; c0 += 64) {
            // ---- stage A and B tiles via async global->LDS (16B/lane) ----
#pragma unroll
            for (int q = 0; q < 4; ++q) {
                __builtin_amdgcn_global_load_lds(
                    (const __attribute__((address_space(1))) unsigned int*)(wsrc + q * 16384 + c0),
                    (__attribute__((address_space(3))) unsigned int*)((char*)ash + q * 4096 + t * 16),
                    16, 0, 0);
            }
#pragma unroll
            for (int q = 0; q < 4; ++q) {
                __builtin_amdgcn_global_load_lds(
                    (const __attribute__((address_space(1))) unsigned int*)(xbase + pixoff[q] + c0),
                    (__attribute__((address_space(3))) unsigned int*)((char*)bsh + q * 4096 + t * 16),
                    16, 0, 0);
            }
            __syncthreads();   // drains vmcnt before barrier (compiler-inserted)

            // ---- MFMA on the staged tiles ----
#pragma unroll
            for (int ks = 0; ks < 2; ++ks) {
                const int gq = ks * 4 + quad;
                frag8 af[4], bfr[4];
#pragma unroll
                for (int mt = 0; mt < 4; ++mt) {
                    const int R = wm + mt * 16 + ln15;
                    af[mt] = *(const frag8*)(ashp + R * 64 + ((gq ^ (R & 7)) << 3));
                }
#pragma unroll
                for (int nt = 0; nt < 4; ++nt) {
                    const int R = wn + nt * 16 + ln15;
                    bfr[nt] = *(const frag8*)(bshp + R * 64 + ((gq ^ (R & 7)) << 3));
                }
#pragma unroll
                for (int mt = 0; mt < 4; ++mt)
#pragma unroll
                    for (int nt = 0; nt < 4; ++nt)
                        acc[mt][nt] = __builtin_amdgcn_mfma_f32_16x16x32_bf16(
                            af[mt], bfr[nt], acc[mt][nt], 0, 0, 0);
            }
            __syncthreads();   // protect LDS from next stage
        }
    }

    // ---- epilogue: scale by G*demod[b][o], store fp32 NCHW ----
    const float* scb = sc + b * 512;
    float* outb = out + (size_t)b * 512 * 4096;
#pragma unroll
    for (int mt = 0; mt < 4; ++mt) {
        const int mrow = m0 + wm + mt * 16 + quad * 4;
#pragma unroll
        for (int v = 0; v < 4; ++v) {
            const float s = scb[mrow + v];
            float* orow = outb + (size_t)(mrow + v) * 4096 + p0 + wn + ln15;
#pragma unroll
            for (int nt = 0; nt < 4; ++nt)
                orow[nt * 16] = acc[mt][nt][v] * s;
        }
    }
}

extern "C" void kernel_launch(void* const* d_in, const int* in_sizes, int n_in,
                              void* d_out, int out_size, void* d_ws, size_t ws_size,
                              hipStream_t stream) {
    (void)in_sizes; (void)n_in; (void)out_size; (void)ws_size;
    const float* x      = (const float*)d_in[0];
    const float* w      = (const float*)d_in[1];
    const float* weight = (const float*)d_in[2];
    const float* mw     = (const float*)d_in[3];
    const float* mb     = (const float*)d_in[4];
    float* out = (float*)d_out;

    char* ws = (char*)d_ws;
    float* style         = (float*)(ws + 0);        //  32 KB
    float* sc            = (float*)(ws + 32768);    //  32 KB
    float* wsq           = (float*)(ws + 65536);    //   1 MB
    __hip_bfloat16* wbf  = (__hip_bfloat16*)(ws + 1114112);  // 4.5 MB  [9][512][512]
    __hip_bfloat16* xsp  = (__hip_bfloat16*)(ws + 5832704);  // 68 MB   [16][66][66][512]

    // zero padded borders of xs (interior overwritten by xs_kernel)
    hipMemsetAsync(xsp, 0, (size_t)BATCH * PAD_W * PAD_W * XS_PIX_STRIDE * 2, stream);

    style_kernel<<<dim3(BATCH), dim3(512), 0, stream>>>(w, mw, mb, style);
    wprep_kernel<<<dim3(1024), dim3(256), 0, stream>>>(weight, wsq, wbf);
    demod_kernel<<<dim3(BATCH), dim3(512), 0, stream>>>(style, wsq, sc);
    xs_kernel<<<dim3(64, 8, BATCH), dim3(256), 0, stream>>>(x, style, xsp);
    conv_kernel<<<dim3(32, 4, BATCH), dim3(256), 0, stream>>>(wbf, xsp, sc, out);
}

// Round 2
// 526.593 us; speedup vs baseline: 1.0934x; 1.0934x over previous
//
#include <hip/hip_runtime.h>
#include <hip/hip_bf16.h>

#define IN_CH 512
#define OUT_CH 512
#define HW 64
#define BATCH 16
#define WEIGHT_GAIN 0.014731391274719739f    // 1/sqrt(512*9)
#define MOD_WEIGHT_GAIN 0.04419417382415922f // 1/sqrt(512)

// padded NHWC xs buffer: [B][66][66][512] bf16
#define PAD_W 66
#define XS_PIX_STRIDE 512

typedef __attribute__((ext_vector_type(8))) short frag8;
typedef __attribute__((ext_vector_type(4))) float f32x4;

// ---------------- style[b][i] = (sum_j w[b][j]*mw[i][j])*g + mb[i] ----------------
// one wave per output element; float4 loads + shuffle reduce
__global__ void style_kernel(const float* __restrict__ w, const float* __restrict__ mw,
                             const float* __restrict__ mb, float* __restrict__ style) {
    const int gw = (blockIdx.x * 256 + threadIdx.x) >> 6;  // 0..8191
    const int lane = threadIdx.x & 63;
    const int b = gw >> 9;
    const int i = gw & 511;
    const float4* mwp = (const float4*)(mw + (size_t)i * 512 + lane * 8);
    const float4* wp  = (const float4*)(w + (size_t)b * 512 + lane * 8);
    float4 m0 = mwp[0], m1 = mwp[1];
    float4 w0 = wp[0],  w1 = wp[1];
    float s = m0.x * w0.x + m0.y * w0.y + m0.z * w0.z + m0.w * w0.w
            + m1.x * w1.x + m1.y * w1.y + m1.z * w1.z + m1.w * w1.w;
#pragma unroll
    for (int off = 32; off > 0; off >>= 1) s += __shfl_down(s, off, 64);
    if (lane == 0) style[(size_t)b * 512 + i] = s * MOD_WEIGHT_GAIN + mb[i];
}

// ---------------- wsq[o][i] = G^2 * sum_kk weight^2 ; wbf[kk][o][i] = bf16(weight) ----
__global__ void wprep_kernel(const float* __restrict__ weight, float* __restrict__ wsq,
                             __hip_bfloat16* __restrict__ wbf) {
    const int idx = blockIdx.x * 256 + threadIdx.x;   // 0..262143 = o*512+i
    const float* wp = weight + idx * 9;
    float s = 0.f;
#pragma unroll
    for (int kk = 0; kk < 9; ++kk) {
        float v = wp[kk];
        s += v * v;
        wbf[kk * 262144 + idx] = __float2bfloat16(v);
    }
    wsq[idx] = s * (WEIGHT_GAIN * WEIGHT_GAIN);
}

// ---------------- sc[b][o] = G * rsqrt(sum_i style^2 * wsq + 1e-8) -------------------
// one wave per output element
__global__ void demod_kernel(const float* __restrict__ style, const float* __restrict__ wsq,
                             float* __restrict__ sc) {
    const int gw = (blockIdx.x * 256 + threadIdx.x) >> 6;  // 0..8191
    const int lane = threadIdx.x & 63;
    const int b = gw >> 9;
    const int o = gw & 511;
    const float4* wq = (const float4*)(wsq + (size_t)o * 512 + lane * 8);
    const float4* st = (const float4*)(style + (size_t)b * 512 + lane * 8);
    float4 q0 = wq[0], q1 = wq[1];
    float4 s0 = st[0], s1 = st[1];
    float acc = q0.x * s0.x * s0.x + q0.y * s0.y * s0.y + q0.z * s0.z * s0.z + q0.w * s0.w * s0.w
              + q1.x * s1.x * s1.x + q1.y * s1.y * s1.y + q1.z * s1.z * s1.z + q1.w * s1.w * s1.w;
#pragma unroll
    for (int off = 32; off > 0; off >>= 1) acc += __shfl_down(acc, off, 64);
    if (lane == 0) sc[(size_t)b * 512 + o] = rsqrtf(acc + 1e-8f) * WEIGHT_GAIN;
}

// ---------------- xs_pad[b][y+1][x+1][i] = bf16(style[b][i] * x[b][i][y][x]) ---------
// No LDS: lane = pixel x, wave handles 32 channels. Per channel the 64 lanes read
// 256B fully coalesced; style is wave-uniform (s_load); write 64B contiguous/lane.
__global__ void xs_kernel(const float* __restrict__ x, const float* __restrict__ style,
                          __hip_bfloat16* __restrict__ xsp) {
    const int y = blockIdx.x;            // image row 0..63
    const int b = blockIdx.z;
    const int t = threadIdx.x;
    const int lane = t & 63;             // pixel x
    const int j0 = (blockIdx.y * 4 + (t >> 6)) * 32;   // channel group of 32

    const float* xb = x + (((size_t)b * 512 + j0) * 64 + y) * 64 + lane;
    const float* stb = style + (size_t)b * 512 + j0;
    __hip_bfloat16* dst = xsp + (((size_t)b * PAD_W + (y + 1)) * PAD_W + (lane + 1)) * XS_PIX_STRIDE + j0;

    union { __hip_bfloat16 h[32]; uint4 u[4]; } pk;
#pragma unroll
    for (int k = 0; k < 32; ++k) {
        float v = xb[(size_t)k * 4096];
        pk.h[k] = __float2bfloat16(v * stb[k]);
    }
#pragma unroll
    for (int q = 0; q < 4; ++q) ((uint4*)dst)[q] = pk.u[q];
}

// ---------------- zero only the pad ring: 16 batches x 260 border pixels x 1KB -------
__global__ void border_kernel(__hip_bfloat16* __restrict__ xsp) {
    const int gw = (blockIdx.x * 256 + threadIdx.x) >> 6;  // 0..4159
    const int lane = threadIdx.x & 63;
    const int b = gw / 260;
    const int p = gw % 260;
    int row, col;
    if (p < 66)       { row = 0;            col = p; }
    else if (p < 132) { row = 65;           col = p - 66; }
    else if (p < 196) { row = p - 132 + 1;  col = 0; }
    else              { row = p - 196 + 1;  col = 65; }
    uint4* dst = (uint4*)(xsp + (((size_t)b * PAD_W + row) * PAD_W + col) * XS_PIX_STRIDE);
    dst[lane] = uint4{0, 0, 0, 0};
}

// ---------------- conv: implicit GEMM, M=512(o) x N=4096(p) per batch, K=9*512 -------
// A = wbf[kk][o][i] (bf16, i contiguous), B = xs_pad pixels (bf16, i contiguous)
// 128x128 tile, BK=64, 4 waves each doing 4x4 16x16x32 MFMA tiles.
__global__ void conv_kernel(const __hip_bfloat16* __restrict__ wbf,
                            const __hip_bfloat16* __restrict__ xsp,
                            const float* __restrict__ sc,
                            float* __restrict__ out) {
    __shared__ __hip_bfloat16 ash[128 * 64];
    __shared__ __hip_bfloat16 bsh[128 * 64];

    const int t = threadIdx.x;
    const int p0 = blockIdx.x * 128;   // spatial tile (2 full rows)
    const int m0 = blockIdx.y * 128;   // output-channel tile
    const int b  = blockIdx.z;
    const int y0 = p0 >> 6;

    // --- staging thread mapping: inst q covers tile rows [q*32, q*32+32) ---
    const int r_base = t >> 3;               // 0..31
    const int s_slot = (t & 7) ^ (r_base & 7); // XOR-swizzled source k-group
    const int aoff = (m0 + r_base) * 512 + s_slot * 8;
    int pixoff[4];
#pragma unroll
    for (int q = 0; q < 4; ++q) {
        const int rB = q * 32 + r_base;
        const int yy = y0 + (rB >> 6);       // un-shifted padded row - 0 (tap adds ky)
        const int xx = rB & 63;
        pixoff[q] = (((b * PAD_W) + yy) * PAD_W + xx) * XS_PIX_STRIDE + s_slot * 8;
    }

    // --- compute thread mapping ---
    const int wv = t >> 6;
    const int wm = (wv >> 1) * 64;
    const int wn = (wv & 1) * 64;
    const int lane = t & 63;
    const int ln15 = lane & 15;
    const int quad = lane >> 4;

    f32x4 acc[4][4] = {};

    const short* ashp = (const short*)ash;
    const short* bshp = (const short*)bsh;

    for (int kk = 0; kk < 9; ++kk) {
        const __hip_bfloat16* wsrc = wbf + kk * 262144 + aoff;
        const int shift = ((kk / 3) * PAD_W + (kk % 3)) * XS_PIX_STRIDE;
        const __hip_bfloat16* xbase = xsp + shift;

        for (int c0 = 0; c0 < 512; c0 += 64) {
            // ---- stage A and B tiles via async global->LDS (16B/lane) ----
#pragma unroll
            for (int q = 0; q < 4; ++q) {
                __builtin_amdgcn_global_load_lds(
                    (const __attribute__((address_space(1))) unsigned int*)(wsrc + q * 16384 + c0),
                    (__attribute__((address_space(3))) unsigned int*)((char*)ash + q * 4096 + t * 16),
                    16, 0, 0);
            }
#pragma unroll
            for (int q = 0; q < 4; ++q) {
                __builtin_amdgcn_global_load_lds(
                    (const __attribute__((address_space(1))) unsigned int*)(xbase + pixoff[q] + c0),
                    (__attribute__((address_space(3))) unsigned int*)((char*)bsh + q * 4096 + t * 16),
                    16, 0, 0);
            }
            __syncthreads();   // drains vmcnt before barrier (compiler-inserted)

            // ---- MFMA on the staged tiles ----
#pragma unroll
            for (int ks = 0; ks < 2; ++ks) {
                const int gq = ks * 4 + quad;
                frag8 af[4], bfr[4];
#pragma unroll
                for (int mt = 0; mt < 4; ++mt) {
                    const int R = wm + mt * 16 + ln15;
                    af[mt] = *(const frag8*)(ashp + R * 64 + ((gq ^ (R & 7)) << 3));
                }
#pragma unroll
                for (int nt = 0; nt < 4; ++nt) {
                    const int R = wn + nt * 16 + ln15;
                    bfr[nt] = *(const frag8*)(bshp + R * 64 + ((gq ^ (R & 7)) << 3));
                }
#pragma unroll
                for (int mt = 0; mt < 4; ++mt)
#pragma unroll
                    for (int nt = 0; nt < 4; ++nt)
                        acc[mt][nt] = __builtin_amdgcn_mfma_f32_16x16x32_bf16(
                            af[mt], bfr[nt], acc[mt][nt], 0, 0, 0);
            }
            __syncthreads();   // protect LDS from next stage
        }
    }

    // ---- epilogue: scale by G*demod[b][o], store fp32 NCHW ----
    const float* scb = sc + b * 512;
    float* outb = out + (size_t)b * 512 * 4096;
#pragma unroll
    for (int mt = 0; mt < 4; ++mt) {
        const int mrow = m0 + wm + mt * 16 + quad * 4;
#pragma unroll
        for (int v = 0; v < 4; ++v) {
            const float s = scb[mrow + v];
            float* orow = outb + (size_t)(mrow + v) * 4096 + p0 + wn + ln15;
#pragma unroll
            for (int nt = 0; nt < 4; ++nt)
                orow[nt * 16] = acc[mt][nt][v] * s;
        }
    }
}

extern "C" void kernel_launch(void* const* d_in, const int* in_sizes, int n_in,
                              void* d_out, int out_size, void* d_ws, size_t ws_size,
                              hipStream_t stream) {
    (void)in_sizes; (void)n_in; (void)out_size; (void)ws_size;
    const float* x      = (const float*)d_in[0];
    const float* w      = (const float*)d_in[1];
    const float* weight = (const float*)d_in[2];
    const float* mw     = (const float*)d_in[3];
    const float* mb     = (const float*)d_in[4];
    float* out = (float*)d_out;

    char* ws = (char*)d_ws;
    float* style         = (float*)(ws + 0);        //  32 KB
    float* sc            = (float*)(ws + 32768);    //  32 KB
    float* wsq           = (float*)(ws + 65536);    //   1 MB
    __hip_bfloat16* wbf  = (__hip_bfloat16*)(ws + 1114112);  // 4.5 MB  [9][512][512]
    __hip_bfloat16* xsp  = (__hip_bfloat16*)(ws + 5832704);  // 68 MB   [16][66][66][512]

    wprep_kernel<<<dim3(1024), dim3(256), 0, stream>>>(weight, wsq, wbf);
    style_kernel<<<dim3(2048), dim3(256), 0, stream>>>(w, mw, mb, style);
    demod_kernel<<<dim3(2048), dim3(256), 0, stream>>>(style, wsq, sc);
    border_kernel<<<dim3(1040), dim3(256), 0, stream>>>(xsp);
    xs_kernel<<<dim3(64, 4, BATCH), dim3(256), 0, stream>>>(x, style, xsp);
    conv_kernel<<<dim3(32, 4, BATCH), dim3(256), 0, stream>>>(wbf, xsp, sc, out);
}